// Round 14
// baseline (83.751 us; speedup 1.0000x reference)
//
#include <hip/hip_runtime.h>
#include <hip/hip_bf16.h>

typedef unsigned short ushort_t;
typedef __attribute__((ext_vector_type(8))) short bf16x8;
typedef __attribute__((ext_vector_type(4))) float f32x4;

// Problem constants
#define NROWS 16384          // B*T
#define FDIM  512            // K
#define GE    640            // G*E
#define EDIM  320
#define DDIM  384
#define CB_OFF 12582912      // 16384*768
#define SCAL_OFF 23068672    // CB_OFF + 16384*640
// bf16 W staging at out[0..163840 floats) (quantized region; dead until fused,
// which runs strictly after gemm on the same stream)
#define WB_OFF 0

// bf16 logits for row n are embedded in row n's own cb f32 span:
//   (ushort*)(cb + n*640 + 320)  — reader block == overwriter block, race-free.

// ws layout (floats): [0,640) red_hard | [640,1280) red_soft | [1280,...) slots
#define SLOT_OFF 1280

// ---------------- init accumulators ----------------
__global__ void vq_init_k(float* acc, int n) {
    int i = blockIdx.x * 256 + threadIdx.x;
    if (i < n) acc[i] = 0.0f;
}

// ---------------- fp32 -> bf16 convert (RNE) ----------------
static __device__ __forceinline__ unsigned f2bf(float f) {
    unsigned u = __float_as_uint(f);
    return (u + 0x7FFFu + ((u >> 16) & 1u)) >> 16;
}

static __device__ __forceinline__ uint4 pack8(const float4 v0, const float4 v1) {
    uint4 o;
    o.x = f2bf(v0.x) | (f2bf(v0.y) << 16);
    o.y = f2bf(v0.z) | (f2bf(v0.w) << 16);
    o.z = f2bf(v1.x) | (f2bf(v1.y) << 16);
    o.w = f2bf(v1.z) | (f2bf(v1.w) << 16);
    return o;
}

// W-only convert: 327680 bf16 = 40960 threads x 8
__global__ __launch_bounds__(256) void convert_w_k(
    const float* __restrict__ W, ushort_t* __restrict__ Wb)
{
    const int i = blockIdx.x * 256 + threadIdx.x;
    if (i >= 40960) return;
    const float4 v0 = ((const float4*)W)[i * 2];
    const float4 v1 = ((const float4*)W)[i * 2 + 1];
    *(uint4*)(Wb + (size_t)i * 8) = pack8(v0, v1);
}

// ---------------- async global->LDS helper ----------------
static __device__ __forceinline__ void gload16(const void* g, void* l) {
    __builtin_amdgcn_global_load_lds(
        (const __attribute__((address_space(1))) unsigned int*)g,
        (__attribute__((address_space(3))) unsigned int*)l, 16, 0, 0);
}

// ---------------- MFMA GEMM: logits(bf16, embedded) = bf16(X) @ Wb^T + b ----
// A-staging: reg-staged f32 X -> RNE bf16 -> LDS (deletes the X convert pass;
// f2bf identical to the old convert kernel => logits bit-identical).
__global__ __launch_bounds__(256) void gemm_mfma_k(
    const float* __restrict__ X, const ushort_t* __restrict__ Wb,
    const float* __restrict__ bias, float* __restrict__ L)   // L = cb region base
{
    __shared__ __align__(16) ushort_t As[128 * 32];
    __shared__ __align__(16) ushort_t Bs[128 * 32];

    const int tid  = threadIdx.x;
    const int lane = tid & 63;
    const int wv   = tid >> 6;
    const int wr   = (wv >> 1) * 64;
    const int wc   = (wv & 1) * 64;
    const int row0 = blockIdx.x * 128;
    const int col0 = blockIdx.y * 128;

    const int c0r = tid >> 2;        // 0..63
    const int c0k = (tid & 3) * 8;   // 0,8,16,24

    f32x4 acc[4][4] = {};

    const int rA = lane & 15;
    const int kb = (lane >> 4) * 8;

    for (int t = 0; t < 16; ++t) {
        const int k0 = t * 32;
        // A: two rows' 8-float slivers, f32 -> bf16 in-register
        const float4 a0 = *(const float4*)(X + (size_t)(row0 + c0r) * FDIM + k0 + c0k);
        const float4 a1 = *(const float4*)(X + (size_t)(row0 + c0r) * FDIM + k0 + c0k + 4);
        const float4 a2 = *(const float4*)(X + (size_t)(row0 + 64 + c0r) * FDIM + k0 + c0k);
        const float4 a3 = *(const float4*)(X + (size_t)(row0 + 64 + c0r) * FDIM + k0 + c0k + 4);
        // B: async direct-to-LDS (bf16 W)
        gload16(Wb + (size_t)(col0 + c0r) * FDIM + k0 + c0k,      &Bs[tid * 8]);
        gload16(Wb + (size_t)(col0 + 64 + c0r) * FDIM + k0 + c0k, &Bs[2048 + tid * 8]);
        *(uint4*)&As[c0r * 32 + c0k]        = pack8(a0, a1);
        *(uint4*)&As[(64 + c0r) * 32 + c0k] = pack8(a2, a3);
        __syncthreads();

        bf16x8 af[4], bfr[4];
        #pragma unroll
        for (int mi = 0; mi < 4; ++mi)
            af[mi] = *(const bf16x8*)&As[(wr + mi * 16 + rA) * 32 + kb];
        #pragma unroll
        for (int ni = 0; ni < 4; ++ni)
            bfr[ni] = *(const bf16x8*)&Bs[(wc + ni * 16 + rA) * 32 + kb];

        #pragma unroll
        for (int mi = 0; mi < 4; ++mi)
            #pragma unroll
            for (int ni = 0; ni < 4; ++ni)
                acc[mi][ni] = __builtin_amdgcn_mfma_f32_16x16x32_bf16(
                    af[mi], bfr[ni], acc[mi][ni], 0, 0, 0);
        __syncthreads();
    }

    // C/D map: col = lane&15, row = (lane>>4)*4 + reg; bf16 into upper half
    // of each cb f32 row (embedded layout).
    const int colb = col0 + wc + (lane & 15);
    const int rowb = row0 + wr + (lane >> 4) * 4;
    #pragma unroll
    for (int ni = 0; ni < 4; ++ni) {
        const int col = colb + ni * 16;
        const float bv = bias[col];
        #pragma unroll
        for (int mi = 0; mi < 4; ++mi) {
            const int row = rowb + mi * 16;
            #pragma unroll
            for (int j = 0; j < 4; ++j) {
                ushort_t* lrow = (ushort_t*)(L + (size_t)(row + j) * GE + 320);
                lrow[col] = (ushort_t)f2bf(acc[mi][ni][j] + bv);
            }
        }
    }
}

// ---------------- FUSED scan + emit, 4 rows/block ----------------
// 4096 blocks x 128 threads (2 waves). Block owns 4 rows x both g = 8 units.
// Wave w: units u = w*4 + (lane&3); g = u>>2, nr = u&3. Lane (r=lane&3,
// o=lane>>2) owns elements e = s*64 + o*4 + k (s<5, k<4) of its unit's row.
__global__ __launch_bounds__(128, 8) void vq_fused_k(
    float* __restrict__ Lcb,                 // cb region: bf16 logits in, f32 cb out
    const float* __restrict__ gumbel,
    const float* __restrict__ entries,
    float* __restrict__ qout,                // d_out base (quantized at 0)
    float* __restrict__ red_hard,            // ws[0..640)
    float* __restrict__ slotS,               // ws[SLOT_OFF..)
    int tier)                                // 2=4096 plain, 1=2048 atomic, 0=64 atomic
{
    __shared__ float part[2][320];
    __shared__ float yv_a[8];
    __shared__ int   gi_a[8];

    const int tid  = threadIdx.x;
    const int lane = tid & 63;
    const int w    = tid >> 6;          // wave 0..1
    const int r    = lane & 3;
    const int o    = lane >> 2;         // 0..15
    const int u    = w * 4 + r;         // unit 0..7 == g*4 + nr
    const int g    = u >> 2;            // wave0 -> g0, wave1 -> g1
    const int nr   = u & 3;
    const int n0   = blockIdx.x * 4;
    const int n    = n0 + nr;

    const ushort_t* lrow16 = (const ushort_t*)(Lcb + (size_t)n * GE + 320) + g * EDIM;
    const float* grow = gumbel + ((size_t)n * 2 + g) * EDIM;

    // ---- load own elements (e = s*64 + o*4 + k): bf16 logits + f32 gumbel ----
    f32x4 l4[5], g4[5];
    #pragma unroll
    for (int s = 0; s < 5; ++s) {
        const ushort4 lu = *(const ushort4*)(lrow16 + s * 64 + o * 4);
        l4[s][0] = __uint_as_float((unsigned)lu.x << 16);
        l4[s][1] = __uint_as_float((unsigned)lu.y << 16);
        l4[s][2] = __uint_as_float((unsigned)lu.z << 16);
        l4[s][3] = __uint_as_float((unsigned)lu.w << 16);
        g4[s] = *(const f32x4*)(grow + s * 64 + o * 4);
    }

    // ---- P1: max + argmax (first-index tie-break) ----
    float mh = -3.4e38f, mg = -3.4e38f;
    int hi = 0, gi = 0;
    #pragma unroll
    for (int s = 0; s < 5; ++s) {
        #pragma unroll
        for (int k = 0; k < 4; ++k) {
            const float lv = l4[s][k];
            const float tv = (lv + g4[s][k]) * 0.5f;   // (logits+gumbel)/TAU
            const int e = s * 64 + o * 4 + k;
            if (lv > mh) { mh = lv; hi = e; }
            if (tv > mg) { mg = tv; gi = e; }
        }
    }
    #pragma unroll
    for (int off = 4; off < 64; off <<= 1) {   // merge o-lanes (same r)
        const float om = __shfl_xor(mh, off); const int oi = __shfl_xor(hi, off);
        if (om > mh || (om == mh && oi < hi)) { mh = om; hi = oi; }
        const float om2 = __shfl_xor(mg, off); const int oi2 = __shfl_xor(gi, off);
        if (om2 > mg || (om2 == mg && oi2 < gi)) { mg = om2; gi = oi2; }
    }

    // ---- P2: exps + sums ----
    f32x4 eh[5];
    float sh = 0.f, sg = 0.f;
    #pragma unroll
    for (int s = 0; s < 5; ++s) {
        f32x4 e4;
        #pragma unroll
        for (int k = 0; k < 4; ++k) {
            const float lv = l4[s][k];
            const float tv = (lv + g4[s][k]) * 0.5f;
            const float ev = __expf(lv - mh);
            e4[k] = ev;
            sh += ev;
            sg += __expf(tv - mg);
        }
        eh[s] = e4;
    }
    #pragma unroll
    for (int off = 4; off < 64; off <<= 1) {
        sh += __shfl_xor(sh, off);
        sg += __shfl_xor(sg, off);
    }
    const float ish = 1.0f / sh;
    const float isg = 1.0f / sg;                 // y_soft at its argmax == 1/sg
    const float yv  = (1.0f - isg) + isg;        // straight-through value

    // ---- publish per-unit scalars + hard-count atomic (8/block) ----
    if (o == 0) {
        yv_a[u] = yv;
        gi_a[u] = gi;
        atomicAdd(&red_hard[g * EDIM + hi], 1.0f);
    }

    // ---- soft partials: merge rows (xor 1,2 across r), r==0 writes ----
    #pragma unroll
    for (int s = 0; s < 5; ++s) {
        f32x4 p4;
        #pragma unroll
        for (int k = 0; k < 4; ++k) p4[k] = eh[s][k] * ish;
        #pragma unroll
        for (int off = 1; off < 4; off <<= 1) {
            #pragma unroll
            for (int k = 0; k < 4; ++k) p4[k] += __shfl_xor(p4[k], off);
        }
        if (r == 0) *(f32x4*)&part[w][s * 64 + o * 4] = p4;
    }
    __syncthreads();   // all waves done reading logits before cb overwrite

    // ---- emit cb: 4 rows x 640 = 640 f4, coalesced (overwrites bf16 logits) ----
    #pragma unroll
    for (int it = 0; it < 5; ++it) {
        const int idx = it * 128 + tid;
        const int rr  = idx / 160;
        const int c4  = idx % 160;
        const int gg  = (c4 >= 80) ? 1 : 0;
        const int e4  = (c4 - gg * 80) * 4;
        const int uu  = gg * 4 + rr;
        const int gii = gi_a[uu];
        const float yvv = yv_a[uu];
        f32x4 cv;
        #pragma unroll
        for (int k = 0; k < 4; ++k) cv[k] = (e4 + k == gii) ? yvv : 0.0f;
        *(f32x4*)(Lcb + (size_t)(n0 + rr) * GE + c4 * 4) = cv;
    }

    // ---- emit quantized: 4 rows x 768 = 768 f4, coalesced ----
    #pragma unroll
    for (int it = 0; it < 6; ++it) {
        const int idx = it * 128 + tid;
        const int rr  = idx / 192;
        const int c4  = idx % 192;
        const int gg  = (c4 >= 96) ? 1 : 0;
        const int d4  = (c4 - gg * 96) * 4;
        const int uu  = gg * 4 + rr;
        const int gii = gi_a[uu];
        const float yvv = yv_a[uu];
        const f32x4 ev = *(const f32x4*)(entries + ((size_t)(gg * EDIM + gii)) * DDIM + d4);
        f32x4 qv;
        #pragma unroll
        for (int k = 0; k < 4; ++k) qv[k] = yvv * ev[k];
        *(f32x4*)(qout + (size_t)(n0 + rr) * 768 + c4 * 4) = qv;
    }

    // ---- sink soft partials: one 640-float row per block ----
    for (int e = tid; e < 640; e += 128) {
        const int gg = e / 320, ee = e % 320;
        const float s = part[gg][ee];
        if (tier == 2)      slotS[(size_t)blockIdx.x * 640 + e] = s;
        else if (tier == 1) atomicAdd(&slotS[(size_t)(blockIdx.x & 2047) * 640 + e], s);
        else                atomicAdd(&slotS[(size_t)(blockIdx.x & 63) * 640 + e], s);
    }
}

// ---------------- slot reduction, parallel chunked ----------------
__global__ __launch_bounds__(256) void reduce_soft3_k(
    const float* __restrict__ slotS, int nrows, float* __restrict__ red_soft)
{
    const int gid = blockIdx.x * 256 + threadIdx.x;
    const int nchunk = nrows / 32;
    if (gid >= 640 * nchunk) return;
    const int col   = gid % 640;
    const int chunk = gid / 640;
    const int base  = chunk * 32;
    float a0 = 0.f, a1 = 0.f, a2 = 0.f, a3 = 0.f;
    #pragma unroll
    for (int k = 0; k < 32; k += 4) {
        a0 += slotS[(size_t)(base + k + 0) * 640 + col];
        a1 += slotS[(size_t)(base + k + 1) * 640 + col];
        a2 += slotS[(size_t)(base + k + 2) * 640 + col];
        a3 += slotS[(size_t)(base + k + 3) * 640 + col];
    }
    atomicAdd(&red_soft[col], (a0 + a1) + (a2 + a3));   // <=128 RMW per address
}

// ---------------- perplexities ----------------
__global__ void vq_final_k(const float* __restrict__ red_hard,
                           const float* __restrict__ red_soft,
                           float* __restrict__ out)
{
    const int lane = threadIdx.x & 63;
    float code = 0.f, prob = 0.f;
    for (int g = 0; g < 2; ++g) {
        float shh = 0.f, sss = 0.f;
        #pragma unroll
        for (int j = 0; j < 5; ++j) {
            const int e = g * EDIM + lane + j * 64;
            const float ph = red_hard[e] * (1.0f / 16384.0f);
            const float ps = red_soft[e] * (1.0f / 16384.0f);
            shh += ph * __logf(ph + 1e-7f);
            sss += ps * __logf(ps + 1e-7f);
        }
        #pragma unroll
        for (int off = 32; off > 0; off >>= 1) {
            shh += __shfl_xor(shh, off);
            sss += __shfl_xor(sss, off);
        }
        code += __expf(-shh);
        prob += __expf(-sss);
    }
    if (threadIdx.x == 0) {
        out[SCAL_OFF + 0] = code;
        out[SCAL_OFF + 1] = prob;
    }
}

extern "C" void kernel_launch(void* const* d_in, const int* in_sizes, int n_in,
                              void* d_out, int out_size, void* d_ws, size_t ws_size,
                              hipStream_t stream) {
    const float* x       = (const float*)d_in[0];
    const float* proj_w  = (const float*)d_in[1];
    const float* proj_b  = (const float*)d_in[2];
    const float* entries = (const float*)d_in[3];
    const float* gumbel  = (const float*)d_in[4];
    float* out = (float*)d_out;
    float* ws  = (float*)d_ws;
    float* cb = out + CB_OFF;                       // cb region (logits embedded)
    ushort_t* Wb = (ushort_t*)(out + WB_OFF);       // bf16 W (dead before fused)

    float* red_hard = ws;            // 640 floats
    float* red_soft = ws + 640;      // 640 floats
    float* slotS    = ws + SLOT_OFF;

    const size_t needA = (size_t)(SLOT_OFF + 4096 * 640) * 4;
    const size_t needB = (size_t)(SLOT_OFF + 2048 * 640) * 4;
    const int tier  = (ws_size >= needA) ? 2 : (ws_size >= needB) ? 1 : 0;
    const int nrows = (tier == 2) ? 4096 : (tier == 1) ? 2048 : 64;
    // tier 2: slot rows fully overwritten -> zero only 1280 reduction floats;
    // tiers 1/0: atomic accumulation -> zero the slot rows too.
    const int nz = (tier == 2) ? 1280 : (SLOT_OFF + nrows * 640);
    const int redblocks = (640 * (nrows / 32) + 255) / 256;

    hipLaunchKernelGGL(vq_init_k, dim3((nz + 255) / 256), dim3(256), 0, stream,
                       ws, nz);
    hipLaunchKernelGGL(convert_w_k, dim3(160), dim3(256), 0, stream,
                       proj_w, Wb);
    hipLaunchKernelGGL(gemm_mfma_k, dim3(NROWS / 128, GE / 128), dim3(256), 0, stream,
                       x, Wb, proj_b, cb);
    hipLaunchKernelGGL(vq_fused_k, dim3(4096), dim3(128), 0, stream,
                       cb, gumbel, entries, out, red_hard, slotS, tier);
    hipLaunchKernelGGL(reduce_soft3_k, dim3(redblocks), dim3(256), 0, stream,
                       slotS, nrows, red_soft);
    hipLaunchKernelGGL(vq_final_k, dim3(1), dim3(64), 0, stream,
                       red_hard, red_soft, out);
}

// Round 15
// 74.266 us; speedup vs baseline: 1.1277x; 1.1277x over previous
//
#include <hip/hip_runtime.h>
#include <hip/hip_bf16.h>

typedef unsigned short ushort_t;
typedef __attribute__((ext_vector_type(8))) short bf16x8;
typedef __attribute__((ext_vector_type(4))) float f32x4;

// Problem constants
#define NROWS 16384          // B*T
#define FDIM  512            // K
#define GE    640            // G*E
#define EDIM  320
#define DDIM  384
#define CB_OFF 12582912      // 16384*768
#define SCAL_OFF 23068672    // CB_OFF + 16384*640
// bf16 staging inside out[quantized region] (dead after gemm)
#define XB_OFF 0
#define WB_OFF 4194304

// bf16 logits for row n are embedded in row n's own cb f32 span:
//   (ushort*)(cb + n*640 + 320)  — reader block == overwriter block, race-free.

// ws layout (floats): [0,640) red_hard | [640,1280) red_soft | [1280,...) slots
#define SLOT_OFF 1280
#define SLOT_BIG_ROWS 2048   // plain-store path: 2048 rows x 640 floats = 5.2 MB
#define SLOT_SMALL_COPIES 64 // atomic fallback

// ---------------- init accumulators ----------------
__global__ void vq_init_k(float* acc, int n) {
    int i = blockIdx.x * 256 + threadIdx.x;
    if (i < n) acc[i] = 0.0f;
}

// ---------------- fp32 -> bf16 convert (RNE) ----------------
static __device__ __forceinline__ unsigned f2bf(float f) {
    unsigned u = __float_as_uint(f);
    return (u + 0x7FFFu + ((u >> 16) & 1u)) >> 16;
}

__global__ __launch_bounds__(256) void convert_bf16_k(
    const float* __restrict__ X, const float* __restrict__ W,
    ushort_t* __restrict__ Xb, ushort_t* __restrict__ Wb)
{
    const size_t i = (size_t)blockIdx.x * 256 + threadIdx.x;
    const float4* src;
    ushort_t* dst;
    if (i < 1048576) {
        src = (const float4*)X + i * 2;
        dst = Xb + i * 8;
    } else {
        const size_t j = i - 1048576;
        src = (const float4*)W + j * 2;
        dst = Wb + j * 8;
    }
    const float4 v0 = src[0], v1 = src[1];
    uint4 o;
    o.x = f2bf(v0.x) | (f2bf(v0.y) << 16);
    o.y = f2bf(v0.z) | (f2bf(v0.w) << 16);
    o.z = f2bf(v1.x) | (f2bf(v1.y) << 16);
    o.w = f2bf(v1.z) | (f2bf(v1.w) << 16);
    *(uint4*)dst = o;
}

// ---------------- async global->LDS helper ----------------
static __device__ __forceinline__ void gload16(const void* g, void* l) {
    __builtin_amdgcn_global_load_lds(
        (const __attribute__((address_space(1))) unsigned int*)g,
        (__attribute__((address_space(3))) unsigned int*)l, 16, 0, 0);
}

// ---------------- nontemporal store helper ----------------
static __device__ __forceinline__ void nts4(float* p, f32x4 v) {
    __builtin_nontemporal_store(v, (f32x4*)p);
}

// ---------------- MFMA GEMM: logits(bf16, embedded) = Xb @ Wb^T + b ----------------
__global__ __launch_bounds__(256) void gemm_mfma_k(
    const ushort_t* __restrict__ Xb, const ushort_t* __restrict__ Wb,
    const float* __restrict__ bias, float* __restrict__ L)   // L = cb region base
{
    __shared__ __align__(16) ushort_t As[128 * 32];
    __shared__ __align__(16) ushort_t Bs[128 * 32];

    const int tid  = threadIdx.x;
    const int lane = tid & 63;
    const int wv   = tid >> 6;
    const int wr   = (wv >> 1) * 64;
    const int wc   = (wv & 1) * 64;
    const int row0 = blockIdx.x * 128;
    const int col0 = blockIdx.y * 128;

    const int c0r = tid >> 2;
    const int c0k = (tid & 3) * 8;

    f32x4 acc[4][4] = {};

    const int rA = lane & 15;
    const int kb = (lane >> 4) * 8;

    for (int t = 0; t < 16; ++t) {
        const int k0 = t * 32;
        gload16(Xb + (size_t)(row0 + c0r) * FDIM + k0 + c0k,        &As[tid * 8]);
        gload16(Xb + (size_t)(row0 + 64 + c0r) * FDIM + k0 + c0k,   &As[2048 + tid * 8]);
        gload16(Wb + (size_t)(col0 + c0r) * FDIM + k0 + c0k,        &Bs[tid * 8]);
        gload16(Wb + (size_t)(col0 + 64 + c0r) * FDIM + k0 + c0k,   &Bs[2048 + tid * 8]);
        __syncthreads();

        bf16x8 af[4], bfr[4];
        #pragma unroll
        for (int mi = 0; mi < 4; ++mi)
            af[mi] = *(const bf16x8*)&As[(wr + mi * 16 + rA) * 32 + kb];
        #pragma unroll
        for (int ni = 0; ni < 4; ++ni)
            bfr[ni] = *(const bf16x8*)&Bs[(wc + ni * 16 + rA) * 32 + kb];

        #pragma unroll
        for (int mi = 0; mi < 4; ++mi)
            #pragma unroll
            for (int ni = 0; ni < 4; ++ni)
                acc[mi][ni] = __builtin_amdgcn_mfma_f32_16x16x32_bf16(
                    af[mi], bfr[ni], acc[mi][ni], 0, 0, 0);
        __syncthreads();
    }

    // C/D map: col = lane&15, row = (lane>>4)*4 + reg; bf16 into upper half
    // of each cb f32 row (embedded layout).
    const int colb = col0 + wc + (lane & 15);
    const int rowb = row0 + wr + (lane >> 4) * 4;
    #pragma unroll
    for (int ni = 0; ni < 4; ++ni) {
        const int col = colb + ni * 16;
        const float bv = bias[col];
        #pragma unroll
        for (int mi = 0; mi < 4; ++mi) {
            const int row = rowb + mi * 16;
            #pragma unroll
            for (int j = 0; j < 4; ++j) {
                ushort_t* lrow = (ushort_t*)(L + (size_t)(row + j) * GE + 320);
                lrow[col] = (ushort_t)f2bf(acc[mi][ni][j] + bv);
            }
        }
    }
}

// ---------------- FUSED scan + emit, bf16 logits (R13 structure + NT emit) ----
// 2048 blocks x 256 threads (4 waves). Block owns 8 rows x both g = 16 units.
// Wave w: units u = w*4 + (lane&3); u = g*8 + nr. Lane (r = lane&3, o = lane>>2)
// owns elements e = s*64 + o*4 + k (s<5, k<4) of its unit's row.
__global__ __launch_bounds__(256, 6) void vq_fused_k(
    float* __restrict__ Lcb,                 // cb region: bf16 logits in, f32 cb out
    const float* __restrict__ gumbel,
    const float* __restrict__ entries,
    float* __restrict__ qout,                // d_out base (quantized at 0)
    float* __restrict__ red_hard,            // ws[0..640)
    float* __restrict__ slotS,               // ws[SLOT_OFF..)
    int mode)                                // 1 = plain slots, 0 = atomic copies
{
    __shared__ float part[4][320];
    __shared__ float yv_a[16];
    __shared__ int   gi_a[16];

    const int tid  = threadIdx.x;
    const int lane = tid & 63;
    const int w    = tid >> 6;          // wave 0..3
    const int r    = lane & 3;
    const int o    = lane >> 2;         // 0..15
    const int u    = w * 4 + r;         // unit 0..15 == g*8 + nr
    const int g    = u >> 3;
    const int nr   = u & 7;
    const int n0   = blockIdx.x * 8;
    const int n    = n0 + nr;

    const ushort_t* lrow16 = (const ushort_t*)(Lcb + (size_t)n * GE + 320) + g * EDIM;
    const float* grow = gumbel + ((size_t)n * 2 + g) * EDIM;

    // ---- load own elements (e = s*64 + o*4 + k): bf16 logits + f32 gumbel ----
    f32x4 l4[5], g4[5];
    #pragma unroll
    for (int s = 0; s < 5; ++s) {
        const ushort4 lu = *(const ushort4*)(lrow16 + s * 64 + o * 4);
        l4[s][0] = __uint_as_float((unsigned)lu.x << 16);
        l4[s][1] = __uint_as_float((unsigned)lu.y << 16);
        l4[s][2] = __uint_as_float((unsigned)lu.z << 16);
        l4[s][3] = __uint_as_float((unsigned)lu.w << 16);
        g4[s] = *(const f32x4*)(grow + s * 64 + o * 4);
    }

    // ---- P1: max + argmax (first-index tie-break, exact on bf16 values) ----
    float mh = -3.4e38f, mg = -3.4e38f;
    int hi = 0, gi = 0;
    #pragma unroll
    for (int s = 0; s < 5; ++s) {
        #pragma unroll
        for (int k = 0; k < 4; ++k) {
            const float lv = l4[s][k];
            const float tv = (lv + g4[s][k]) * 0.5f;   // (logits+gumbel)/TAU
            const int e = s * 64 + o * 4 + k;
            if (lv > mh) { mh = lv; hi = e; }
            if (tv > mg) { mg = tv; gi = e; }
        }
    }
    #pragma unroll
    for (int off = 4; off < 64; off <<= 1) {   // merge o-lanes (same r)
        const float om = __shfl_xor(mh, off); const int oi = __shfl_xor(hi, off);
        if (om > mh || (om == mh && oi < hi)) { mh = om; hi = oi; }
        const float om2 = __shfl_xor(mg, off); const int oi2 = __shfl_xor(gi, off);
        if (om2 > mg || (om2 == mg && oi2 < gi)) { mg = om2; gi = oi2; }
    }

    // ---- P2: exps + sums ----
    f32x4 eh[5];
    float sh = 0.f, sg = 0.f;
    #pragma unroll
    for (int s = 0; s < 5; ++s) {
        f32x4 e4;
        #pragma unroll
        for (int k = 0; k < 4; ++k) {
            const float lv = l4[s][k];
            const float tv = (lv + g4[s][k]) * 0.5f;
            const float ev = __expf(lv - mh);
            e4[k] = ev;
            sh += ev;
            sg += __expf(tv - mg);
        }
        eh[s] = e4;
    }
    #pragma unroll
    for (int off = 4; off < 64; off <<= 1) {
        sh += __shfl_xor(sh, off);
        sg += __shfl_xor(sg, off);
    }
    const float ish = 1.0f / sh;
    const float isg = 1.0f / sg;                 // y_soft at its argmax == 1/sg
    const float yv  = (1.0f - isg) + isg;        // straight-through value

    // ---- publish per-unit scalars + hard-count atomic (16/block) ----
    if (o == 0) {
        yv_a[u] = yv;
        gi_a[u] = gi;
        atomicAdd(&red_hard[g * EDIM + hi], 1.0f);
    }

    // ---- soft partials: merge rows (xor 1,2 across r), r==0 writes ----
    #pragma unroll
    for (int s = 0; s < 5; ++s) {
        f32x4 p4;
        #pragma unroll
        for (int k = 0; k < 4; ++k) p4[k] = eh[s][k] * ish;
        #pragma unroll
        for (int off = 1; off < 4; off <<= 1) {
            #pragma unroll
            for (int k = 0; k < 4; ++k) p4[k] += __shfl_xor(p4[k], off);
        }
        if (r == 0) *(f32x4*)&part[w][s * 64 + o * 4] = p4;
    }
    __syncthreads();   // all waves done reading logits before cb overwrite

    // ---- emit cb: 8 rows x 640 = 1280 f4, coalesced, NONTEMPORAL ----
    #pragma unroll
    for (int it = 0; it < 5; ++it) {
        const int idx = it * 256 + tid;
        const int rr  = idx / 160;
        const int c4  = idx % 160;
        const int gg  = (c4 >= 80) ? 1 : 0;
        const int e4  = (c4 - gg * 80) * 4;
        const int uu  = gg * 8 + rr;
        const int gii = gi_a[uu];
        const float yvv = yv_a[uu];
        f32x4 cv;
        #pragma unroll
        for (int k = 0; k < 4; ++k) cv[k] = (e4 + k == gii) ? yvv : 0.0f;
        nts4(Lcb + (size_t)(n0 + rr) * GE + c4 * 4, cv);
    }

    // ---- emit quantized: 8 rows x 768 = 1536 f4, coalesced, NONTEMPORAL ----
    #pragma unroll
    for (int it = 0; it < 6; ++it) {
        const int idx = it * 256 + tid;
        const int rr  = idx / 192;
        const int c4  = idx % 192;
        const int gg  = (c4 >= 96) ? 1 : 0;
        const int d4  = (c4 - gg * 96) * 4;
        const int uu  = gg * 8 + rr;
        const int gii = gi_a[uu];
        const float yvv = yv_a[uu];
        const f32x4 ev = *(const f32x4*)(entries + ((size_t)(gg * EDIM + gii)) * DDIM + d4);
        f32x4 qv;
        #pragma unroll
        for (int k = 0; k < 4; ++k) qv[k] = yvv * ev[k];
        nts4(qout + (size_t)(n0 + rr) * 768 + c4 * 4, qv);
    }

    // ---- sink soft partials: one 640-float row per block (cached; re-read) ----
    for (int e = tid; e < 640; e += 256) {
        const int gg = e / 320, ee = e % 320;
        const float s = part[gg * 2][ee] + part[gg * 2 + 1][ee];
        if (mode == 1) {
            slotS[(size_t)blockIdx.x * 640 + e] = s;
        } else {
            atomicAdd(&slotS[(size_t)(blockIdx.x & (SLOT_SMALL_COPIES - 1)) * 640 + e], s);
        }
    }
}

// ---------------- slot reduction, parallel chunked ----------------
__global__ __launch_bounds__(256) void reduce_soft3_k(
    const float* __restrict__ slotS, int nrows, float* __restrict__ red_soft)
{
    const int gid = blockIdx.x * 256 + threadIdx.x;
    const int nchunk = nrows / 32;
    if (gid >= 640 * nchunk) return;
    const int col   = gid % 640;
    const int chunk = gid / 640;
    const int base  = chunk * 32;
    float a0 = 0.f, a1 = 0.f, a2 = 0.f, a3 = 0.f;
    #pragma unroll
    for (int k = 0; k < 32; k += 4) {
        a0 += slotS[(size_t)(base + k + 0) * 640 + col];
        a1 += slotS[(size_t)(base + k + 1) * 640 + col];
        a2 += slotS[(size_t)(base + k + 2) * 640 + col];
        a3 += slotS[(size_t)(base + k + 3) * 640 + col];
    }
    atomicAdd(&red_soft[col], (a0 + a1) + (a2 + a3));   // <=64 RMW per address
}

// ---------------- perplexities ----------------
__global__ void vq_final_k(const float* __restrict__ red_hard,
                           const float* __restrict__ red_soft,
                           float* __restrict__ out)
{
    const int lane = threadIdx.x & 63;
    float code = 0.f, prob = 0.f;
    for (int g = 0; g < 2; ++g) {
        float shh = 0.f, sss = 0.f;
        #pragma unroll
        for (int j = 0; j < 5; ++j) {
            const int e = g * EDIM + lane + j * 64;
            const float ph = red_hard[e] * (1.0f / 16384.0f);
            const float ps = red_soft[e] * (1.0f / 16384.0f);
            shh += ph * __logf(ph + 1e-7f);
            sss += ps * __logf(ps + 1e-7f);
        }
        #pragma unroll
        for (int off = 32; off > 0; off >>= 1) {
            shh += __shfl_xor(shh, off);
            sss += __shfl_xor(sss, off);
        }
        code += __expf(-shh);
        prob += __expf(-sss);
    }
    if (threadIdx.x == 0) {
        out[SCAL_OFF + 0] = code;
        out[SCAL_OFF + 1] = prob;
    }
}

extern "C" void kernel_launch(void* const* d_in, const int* in_sizes, int n_in,
                              void* d_out, int out_size, void* d_ws, size_t ws_size,
                              hipStream_t stream) {
    const float* x       = (const float*)d_in[0];
    const float* proj_w  = (const float*)d_in[1];
    const float* proj_b  = (const float*)d_in[2];
    const float* entries = (const float*)d_in[3];
    const float* gumbel  = (const float*)d_in[4];
    float* out = (float*)d_out;
    float* ws  = (float*)d_ws;
    float* cb = out + CB_OFF;                       // cb region (logits embedded)
    ushort_t* Xb = (ushort_t*)(out + XB_OFF);
    ushort_t* Wb = (ushort_t*)(out + WB_OFF);

    float* red_hard = ws;            // 640 floats
    float* red_soft = ws + 640;      // 640 floats
    float* slotS    = ws + SLOT_OFF;

    const size_t need1 = (size_t)(SLOT_OFF + SLOT_BIG_ROWS * 640) * 4;
    const int mode  = (ws_size >= need1) ? 1 : 0;
    const int nrows = (mode == 1) ? SLOT_BIG_ROWS : SLOT_SMALL_COPIES;
    const int nz = (mode == 1) ? 1280 : (SLOT_OFF + SLOT_SMALL_COPIES * 640);
    const int redblocks = (640 * (nrows / 32) + 255) / 256;

    hipLaunchKernelGGL(vq_init_k, dim3((nz + 255) / 256), dim3(256), 0, stream,
                       ws, nz);
    hipLaunchKernelGGL(convert_bf16_k, dim3(4256), dim3(256), 0, stream,
                       x, proj_w, Xb, Wb);
    hipLaunchKernelGGL(gemm_mfma_k, dim3(NROWS / 128, GE / 128), dim3(256), 0, stream,
                       Xb, Wb, proj_b, cb);
    hipLaunchKernelGGL(vq_fused_k, dim3(2048), dim3(256), 0, stream,
                       cb, gumbel, entries, out, red_hard, slotS, mode);
    hipLaunchKernelGGL(reduce_soft3_k, dim3(redblocks), dim3(256), 0, stream,
                       slotS, nrows, red_soft);
    hipLaunchKernelGGL(vq_final_k, dim3(1), dim3(64), 0, stream,
                       red_hard, red_soft, out);
}